// Round 2
// baseline (239.904 us; speedup 1.0000x reference)
//
#include <hip/hip_runtime.h>
#include <math.h>

#define HF 96
#define WF 160
#define CH 100
#define HH 48      // HF/2
#define HW 80      // WF/2
#define NPIX (HH*HW)   // 3840
#define MD 9
#define KD 19
#define K2 361

// ws float offsets
#define OFF_XT 0
#define OFF_YT (CH*NPIX)
#define OFF_XS (2*CH*NPIX)
#define OFF_YS (2*CH*NPIX + NPIX)
#define OFF_DH (2*CH*NPIX + 2*NPIX)
// total = 775680 + 1386240 = 2161920 floats (~8.65 MB)

// ---------------- Kernel A: pool + norms, channel-major outputs ----------------
__global__ __launch_bounds__(128) void pool_kernel(
    const float* __restrict__ q, const float* __restrict__ p,
    float* __restrict__ Xt, float* __restrict__ Yt,
    float* __restrict__ xs, float* __restrict__ ys) {
  int pix = blockIdx.x;
  int i = pix / HW, j = pix % HW;
  int c = threadIdx.x;
  __shared__ float red[2][128];
  float xv = 0.f, yv = 0.f;
  if (c < CH) {
    int base = (2 * i) * WF * CH + (2 * j) * CH + c;
    xv = 0.25f * (q[base] + q[base + CH] + q[base + WF * CH] + q[base + WF * CH + CH]);
    yv = 0.25f * (p[base] + p[base + CH] + p[base + WF * CH] + p[base + WF * CH + CH]);
    Xt[c * NPIX + pix] = xv;
    Yt[c * NPIX + pix] = yv;
  }
  red[0][c] = xv * xv;
  red[1][c] = yv * yv;
  __syncthreads();
  for (int s = 64; s > 0; s >>= 1) {
    if (c < s) { red[0][c] += red[0][c + s]; red[1][c] += red[1][c + s]; }
    __syncthreads();
  }
  if (c == 0) { xs[pix] = red[0][0]; ys[pix] = red[1][0]; }
}

// ---------------- Kernel B: register-blocked local correlation ----------------
// Block: 16-px strip of one half-res row. Threads: (half h of channels) x
// (4-px group g) x (dy). Each thread: acc[4 px][19 dx] over its 50 channels.
#define WT 16
#define NG 4          // 4-px groups per strip
#define CC 5          // channels staged per round (per half)
#define CHALF 50
#define NROUND (CHALF/CC)   // 10
#define YCOLS 36      // 34 needed + 2 pad (mult of 4 for float4 align)
#define NUNIT (NG*KD) // 76 threads per half
#define TPB 160       // 2*NUNIT = 152 active

__global__ __launch_bounds__(TPB) void dist_kernel(
    const float* __restrict__ Xt, const float* __restrict__ Yt,
    const float* __restrict__ xs, const float* __restrict__ ys,
    float* __restrict__ dh) {
  int b = blockIdx.x;
  int i = b / 5;              // half-res row
  int j0 = (b - i * 5) * WT;  // strip start
  int t = threadIdx.x;
  int h = t / NUNIT;          // 0 or 1 (2 = idle tail)
  int u = t - h * NUNIT;
  int g = u & 3;
  int dy = u >> 2;
  bool active = (t < 2 * NUNIT);

  __shared__ __align__(16) float ytile[2 * CC * KD * YCOLS];  // 6840 floats
  __shared__ __align__(16) float xtile[2 * CC * WT];          // 160 floats

  float acc[NG][KD];
#pragma unroll
  for (int e = 0; e < NG; ++e)
#pragma unroll
    for (int d = 0; d < KD; ++d) acc[e][d] = 0.f;

  for (int rnd = 0; rnd < NROUND; ++rnd) {
    __syncthreads();
    // stage 2 halves x CC channels of the y-window and x-strip
    for (int idx = t; idx < 2 * CC * KD * YCOLS; idx += TPB) {
      int col = idx % YCOLS;
      int r1 = idx / YCOLS;
      int row = r1 % KD;
      int hc = r1 / KD;               // (half*CC + cc)
      int cg = (hc / CC) * CHALF + rnd * CC + (hc % CC);
      int grow = i - MD + row;
      int gcol = j0 - MD + col;
      float v = 0.f;
      if (grow >= 0 && grow < HH && gcol >= 0 && gcol < HW && col < WT + 2 * MD)
        v = Yt[cg * NPIX + grow * HW + gcol];
      ytile[idx] = v;
    }
    {
      int idx = t;
      if (idx < 2 * CC * WT) {
        int px = idx % WT;
        int hc = idx / WT;
        int cg = (hc / CC) * CHALF + rnd * CC + (hc % CC);
        xtile[idx] = Xt[cg * NPIX + i * HW + j0 + px];
      }
    }
    __syncthreads();
    if (active) {
#pragma unroll
      for (int cc = 0; cc < CC; ++cc) {
        const float* yb = &ytile[((h * CC + cc) * KD + dy) * YCOLS + 4 * g];
        float4 y4[6];
#pragma unroll
        for (int q4 = 0; q4 < 6; ++q4) y4[q4] = *(const float4*)(yb + 4 * q4);
        const float* ya = (const float*)y4;
        float4 xv = *(const float4*)&xtile[(h * CC + cc) * WT + 4 * g];
        float xe[4] = {xv.x, xv.y, xv.z, xv.w};
#pragma unroll
        for (int e = 0; e < NG; ++e)
#pragma unroll
          for (int d = 0; d < KD; ++d)
            acc[e][d] = fmaf(xe[e], ya[e + d], acc[e][d]);
      }
    }
  }

  // cross-half combine through LDS (reuse ytile as scratch)
  float* scratch = ytile;
  __syncthreads();
  if (h == 1) {
#pragma unroll
    for (int e = 0; e < NG; ++e)
#pragma unroll
      for (int d = 0; d < KD; ++d)
        scratch[u * 77 + e * KD + d] = acc[e][d];
  }
  __syncthreads();
  if (h == 0) {
#pragma unroll
    for (int e = 0; e < NG; ++e)
#pragma unroll
      for (int d = 0; d < KD; ++d)
        acc[e][d] += scratch[u * 77 + e * KD + d];
  }
  __syncthreads();
  // transform + stage results pixel-major in LDS for coalesced store
  if (h == 0) {
    int ii = i + dy - MD;
#pragma unroll
    for (int e = 0; e < NG; ++e) {
      int jb = j0 + 4 * g + e;
      int pix = i * HW + jb;
      float xss = xs[pix];
#pragma unroll
      for (int d = 0; d < KD; ++d) {
        int jj = jb + d - MD;
        float r = 1.0f;
        if (ii >= 0 && ii < HH && jj >= 0 && jj < HW) {
          int np = ii * HW + jj;
          float s = xss + ys[np] - 2.f * acc[e][d];
          float ex = __expf(-s);
          r = (1.f - ex) / (1.f + ex);
        }
        scratch[(4 * g + e) * K2 + dy * KD + d] = r;
      }
    }
  }
  __syncthreads();
  for (int idx = t; idx < WT * K2; idx += TPB) {
    int px = idx / K2;
    int o = idx - px * K2;
    dh[(i * HW + j0 + px) * K2 + o] = scratch[idx];
  }
}

// ---------------- Kernel C: bilinear upsample + per-object masked min ----------------
#define NMAX 8
__global__ __launch_bounds__(256) void upmin_kernel(
    const float* __restrict__ dh, const int* __restrict__ labels,
    const int* __restrict__ gt, int n, float* __restrict__ out) {
  int wid = threadIdx.x >> 6;
  int lane = threadIdx.x & 63;
  int pixel = blockIdx.x * 4 + wid;
  int I = pixel / WF, J = pixel - I * WF;

  const float sy = (float)((HH - 1.0) / (HF - 1.0));
  const float sx = (float)((HW - 1.0) / (WF - 1.0));
  float py = (float)I * sy;
  int y0 = (int)floorf(py); if (y0 > HH - 2) y0 = HH - 2; if (y0 < 0) y0 = 0;
  float fy = py - (float)y0;
  float px = (float)J * sx;
  int x0 = (int)floorf(px); if (x0 > HW - 2) x0 = HW - 2; if (x0 < 0) x0 = 0;
  float fx = px - (float)x0;

  const float* r00 = dh + (y0 * HW + x0) * K2;
  const float* r01 = r00 + K2;
  const float* r10 = r00 + HW * K2;
  const float* r11 = r10 + K2;
  float w00 = (1.f - fy) * (1.f - fx), w01 = (1.f - fy) * fx;
  float w10 = fy * (1.f - fx),         w11 = fy * fx;

  int gtl[NMAX];
  for (int o = 0; o < n; ++o) gtl[o] = gt[o];
  float mins[NMAX];
  for (int o = 0; o < NMAX; ++o) mins[o] = 1.0f;

  for (int k = lane; k < K2; k += 64) {
    int dy = k / KD, dx = k - dy * KD;
    int P = I + dy - MD, Q = J + dx - MD;
    if (P < 0 || P >= HF || Q < 0 || Q >= WF) continue;
    int lab = labels[P * WF + Q];
    float v = w00 * r00[k] + w01 * r01[k] + w10 * r10[k] + w11 * r11[k];
    for (int o = 0; o < n; ++o)
      if (lab == gtl[o]) mins[o] = fminf(mins[o], v);
  }
  for (int s = 32; s > 0; s >>= 1)
    for (int o = 0; o < n; ++o)
      mins[o] = fminf(mins[o], __shfl_down(mins[o], s));
  if (lane == 0)
    for (int o = 0; o < n; ++o) out[pixel * n + o] = mins[o];
}

extern "C" void kernel_launch(void* const* d_in, const int* in_sizes, int n_in,
                              void* d_out, int out_size, void* d_ws, size_t ws_size,
                              hipStream_t stream) {
  const float* prev  = (const float*)d_in[0];
  const float* query = (const float*)d_in[1];
  const int* labels  = (const int*)d_in[2];
  const int* gt      = (const int*)d_in[3];
  int n = in_sizes[3];
  if (n > NMAX) n = NMAX;
  float* ws = (float*)d_ws;
  float* Xt = ws + OFF_XT;
  float* Yt = ws + OFF_YT;
  float* xs = ws + OFF_XS;
  float* ys = ws + OFF_YS;
  float* dh = ws + OFF_DH;
  float* out = (float*)d_out;

  hipLaunchKernelGGL(pool_kernel, dim3(NPIX), dim3(128), 0, stream,
                     query, prev, Xt, Yt, xs, ys);
  hipLaunchKernelGGL(dist_kernel, dim3(HH * 5), dim3(TPB), 0, stream,
                     Xt, Yt, xs, ys, dh);
  hipLaunchKernelGGL(upmin_kernel, dim3(HF * WF / 4), dim3(256), 0, stream,
                     dh, labels, gt, n, out);
}

// Round 3
// 168.187 us; speedup vs baseline: 1.4264x; 1.4264x over previous
//
#include <hip/hip_runtime.h>
#include <math.h>

#define HF 96
#define WF 160
#define CH 100
#define HH 48      // HF/2
#define HW 80      // WF/2
#define NPIX 3840  // HH*HW
#define MD 9
#define KD 19
#define K2 361

// ws float offsets
#define OFF_XT 0
#define OFF_YT (CH*NPIX)
#define OFF_XS (2*CH*NPIX)
#define OFF_YS (2*CH*NPIX + NPIX)
#define OFF_DH (2*CH*NPIX + 2*NPIX)

// ---------------- Kernel A: pool + norms, channel-major outputs ----------------
__global__ __launch_bounds__(128) void pool_kernel(
    const float* __restrict__ q, const float* __restrict__ p,
    float* __restrict__ Xt, float* __restrict__ Yt,
    float* __restrict__ xs, float* __restrict__ ys) {
  int pix = blockIdx.x;
  int i = pix / HW, j = pix % HW;
  int c = threadIdx.x;
  __shared__ float red[2][128];
  float xv = 0.f, yv = 0.f;
  if (c < CH) {
    int base = (2 * i) * WF * CH + (2 * j) * CH + c;
    xv = 0.25f * (q[base] + q[base + CH] + q[base + WF * CH] + q[base + WF * CH + CH]);
    yv = 0.25f * (p[base] + p[base + CH] + p[base + WF * CH] + p[base + WF * CH + CH]);
    Xt[c * NPIX + pix] = xv;
    Yt[c * NPIX + pix] = yv;
  }
  red[0][c] = xv * xv;
  red[1][c] = yv * yv;
  __syncthreads();
  for (int s = 64; s > 0; s >>= 1) {
    if (c < s) { red[0][c] += red[0][c + s]; red[1][c] += red[1][c + s]; }
    __syncthreads();
  }
  if (c == 0) { xs[pix] = red[0][0]; ys[pix] = red[1][0]; }
}

// ---------------- Kernel B: local correlation, in-block channel split ----------------
// Block = 4-px strip. Threads = 10 ch-groups x 19 dy = 190 (pad 192, 3 waves).
// Each thread: acc[4 px][19 dx], 10 channels (2 per round x 5 rounds).
// Grid = 48*20 = 960 blocks -> ~2880 waves, 3 blocks/CU (44 KB LDS).
#define TPB 192
#define NACT 190
#define RND 5
#define RCH 20          // channels staged per round
#define YCOL 28         // window cols: j0-12 .. j0+15 (16B-aligned), used 3..24
#define YROW 19
#define YSL (RCH*YROW*(YCOL/4))   // 2660 float4 staging slots

__global__ __launch_bounds__(TPB) void dist_kernel(
    const float* __restrict__ Xt, const float* __restrict__ Yt,
    const float* __restrict__ xs, const float* __restrict__ ys,
    float* __restrict__ dh) {
  int b = blockIdx.x;
  int i = b / 20;
  int j0 = (b - i * 20) * 4;
  int tid = threadIdx.x;
  int g = tid / KD;             // channel group 0..9 (valid when tid<190)
  int dy = tid - g * KD;
  bool active = (tid < NACT);

  __shared__ __align__(16) float ytile[RCH * YROW * YCOL];  // 10640 floats
  __shared__ __align__(16) float xt[CH * 4];                // 400 floats

  // stage x strip (all 100 channels) once
  for (int c = tid; c < CH; c += TPB)
    *(float4*)&xt[c * 4] = *(const float4*)&Xt[c * NPIX + i * HW + j0];

  float acc[4][KD];
#pragma unroll
  for (int e = 0; e < 4; ++e)
#pragma unroll
    for (int d = 0; d < KD; ++d) acc[e][d] = 0.f;

  for (int r = 0; r < RND; ++r) {
    __syncthreads();
    // stage 20 channels of the 19x28 window (coalesced float4 from Yt)
    for (int idx = tid; idx < YSL; idx += TPB) {
      int cl = idx / (YROW * 7);
      int rem = idx - cl * (YROW * 7);
      int row = rem / 7, c4 = rem - row * 7;
      int grow = i - MD + row;
      int flat = grow * HW + (j0 - 12 + c4 * 4);
      flat = flat < 0 ? 0 : (flat > NPIX - 4 ? NPIX - 4 : flat);  // safe clamp; OOB slots unused
      *(float4*)&ytile[idx * 4] = *(const float4*)&Yt[(r * RCH + cl) * NPIX + flat];
    }
    __syncthreads();
    if (active) {
#pragma unroll
      for (int cc = 0; cc < 2; ++cc) {
        int cl = g * 2 + cc;
        const float* yb = &ytile[(cl * YROW + dy) * YCOL];
        float4 y4[7];
#pragma unroll
        for (int q4 = 0; q4 < 7; ++q4) y4[q4] = *(const float4*)(yb + 4 * q4);
        const float* ya = (const float*)y4;
        float4 xv = *(const float4*)&xt[(r * RCH + cl) * 4];
        float xe[4] = {xv.x, xv.y, xv.z, xv.w};
#pragma unroll
        for (int e = 0; e < 4; ++e)
#pragma unroll
          for (int d = 0; d < KD; ++d)
            acc[e][d] = fmaf(xe[e], ya[3 + e + d], acc[e][d]);
      }
    }
  }

  // ---- reduce 10 channel-group partials through LDS (rows of 76 floats) ----
  float* red = ytile;
  float* a = (float*)acc;
  __syncthreads();
  if (active && g >= 5) {
    int k = (g - 5) * KD + dy;
#pragma unroll
    for (int q = 0; q < 76; ++q) red[k * 76 + q] = a[q];
  }
  __syncthreads();
  if (active && g < 5) {
    int k = g * KD + dy;
#pragma unroll
    for (int q = 0; q < 76; ++q) a[q] += red[k * 76 + q];
  }
  __syncthreads();
  if (active && (g == 3 || g == 4)) {
    int k = (g - 3) * KD + dy;
#pragma unroll
    for (int q = 0; q < 76; ++q) red[k * 76 + q] = a[q];
  }
  __syncthreads();
  if (active && (g == 1 || g == 2)) {
    int k = (g - 1) * KD + dy;
#pragma unroll
    for (int q = 0; q < 76; ++q) a[q] += red[k * 76 + q];
  }
  __syncthreads();
  if (active && (g == 1 || g == 2)) {
    int k = (g - 1) * KD + dy;
#pragma unroll
    for (int q = 0; q < 76; ++q) red[k * 76 + q] = a[q];
  }
  __syncthreads();
  if (active && g == 0) {
#pragma unroll
    for (int q = 0; q < 76; ++q)
      red[(40 + dy) * 76 + q] = a[q] + red[dy * 76 + q] + red[(KD + dy) * 76 + q];
  }
  __syncthreads();

  // ---- sigmoid transform + coalesced store ----
  for (int idx = tid; idx < 4 * K2; idx += TPB) {
    int px = idx / K2, off = idx - px * K2;
    int dyo = off / KD, d = off - dyo * KD;
    float dot = red[(40 + dyo) * 76 + px * KD + d];
    int ii = i + dyo - MD, jj = j0 + px + d - MD;
    int pix = i * HW + j0 + px;
    float rr = 1.0f;
    if (ii >= 0 && ii < HH && jj >= 0 && jj < HW) {
      float s = xs[pix] + ys[ii * HW + jj] - 2.f * dot;
      float e = __expf(-s);
      rr = (1.f - e) / (1.f + e);
    }
    dh[pix * K2 + off] = rr;
  }
}

// ---------------- Kernel C: bilinear upsample + per-object masked min ----------------
#define NMAX 8
__global__ __launch_bounds__(256) void upmin_kernel(
    const float* __restrict__ dh, const int* __restrict__ labels,
    const int* __restrict__ gt, int n, float* __restrict__ out) {
  int wid = threadIdx.x >> 6;
  int lane = threadIdx.x & 63;
  int pixel = blockIdx.x * 4 + wid;
  int I = pixel / WF, J = pixel - I * WF;

  const float sy = (float)((HH - 1.0) / (HF - 1.0));
  const float sx = (float)((HW - 1.0) / (WF - 1.0));
  float py = (float)I * sy;
  int y0 = (int)floorf(py); if (y0 > HH - 2) y0 = HH - 2; if (y0 < 0) y0 = 0;
  float fy = py - (float)y0;
  float px = (float)J * sx;
  int x0 = (int)floorf(px); if (x0 > HW - 2) x0 = HW - 2; if (x0 < 0) x0 = 0;
  float fx = px - (float)x0;

  const float* r00 = dh + (y0 * HW + x0) * K2;
  const float* r01 = r00 + K2;
  const float* r10 = r00 + HW * K2;
  const float* r11 = r10 + K2;
  float w00 = (1.f - fy) * (1.f - fx), w01 = (1.f - fy) * fx;
  float w10 = fy * (1.f - fx),         w11 = fy * fx;

  int gtl[NMAX];
  for (int o = 0; o < n; ++o) gtl[o] = gt[o];
  float mins[NMAX];
  for (int o = 0; o < NMAX; ++o) mins[o] = 1.0f;

  for (int k = lane; k < K2; k += 64) {
    int dy = k / KD, dx = k - dy * KD;
    int P = I + dy - MD, Q = J + dx - MD;
    if (P < 0 || P >= HF || Q < 0 || Q >= WF) continue;
    int lab = labels[P * WF + Q];
    float v = w00 * r00[k] + w01 * r01[k] + w10 * r10[k] + w11 * r11[k];
    for (int o = 0; o < n; ++o)
      if (lab == gtl[o]) mins[o] = fminf(mins[o], v);
  }
  for (int s = 32; s > 0; s >>= 1)
    for (int o = 0; o < n; ++o)
      mins[o] = fminf(mins[o], __shfl_down(mins[o], s));
  if (lane == 0)
    for (int o = 0; o < n; ++o) out[pixel * n + o] = mins[o];
}

extern "C" void kernel_launch(void* const* d_in, const int* in_sizes, int n_in,
                              void* d_out, int out_size, void* d_ws, size_t ws_size,
                              hipStream_t stream) {
  const float* prev  = (const float*)d_in[0];
  const float* query = (const float*)d_in[1];
  const int* labels  = (const int*)d_in[2];
  const int* gt      = (const int*)d_in[3];
  int n = in_sizes[3];
  if (n > NMAX) n = NMAX;
  float* ws = (float*)d_ws;
  float* Xt = ws + OFF_XT;
  float* Yt = ws + OFF_YT;
  float* xs = ws + OFF_XS;
  float* ys = ws + OFF_YS;
  float* dh = ws + OFF_DH;
  float* out = (float*)d_out;

  hipLaunchKernelGGL(pool_kernel, dim3(NPIX), dim3(128), 0, stream,
                     query, prev, Xt, Yt, xs, ys);
  hipLaunchKernelGGL(dist_kernel, dim3(960), dim3(TPB), 0, stream,
                     Xt, Yt, xs, ys, dh);
  hipLaunchKernelGGL(upmin_kernel, dim3(HF * WF / 4), dim3(256), 0, stream,
                     dh, labels, gt, n, out);
}